// Round 7
// baseline (2958.032 us; speedup 1.0000x reference)
//
#include <hip/hip_runtime.h>
#include <cstdint>

#define HIDDEN  128
#define NLAYERS 6
#define NNODES  50000
#define NEDGES  640000

typedef short short8 __attribute__((ext_vector_type(8)));
typedef float f32x4  __attribute__((ext_vector_type(4)));

// ---- bf16 <-> f32 helpers (RNE) -------------------------------------------
__device__ __forceinline__ float bf2f(unsigned short u) {
    return __uint_as_float(((unsigned int)u) << 16);
}
__device__ __forceinline__ unsigned short f2bf(float f) {
    unsigned int u = __float_as_uint(f);
    unsigned int r = u + 0x7FFFu + ((u >> 16) & 1u);
    return (unsigned short)(r >> 16);
}
__device__ __forceinline__ unsigned int pack2(float a, float b) {
    return (unsigned int)f2bf(a) | ((unsigned int)f2bf(b) << 16);
}
__device__ __forceinline__ void unpack8(uint4 v, float* f) {
    f[0] = bf2f((unsigned short)(v.x & 0xffff)); f[1] = bf2f((unsigned short)(v.x >> 16));
    f[2] = bf2f((unsigned short)(v.y & 0xffff)); f[3] = bf2f((unsigned short)(v.y >> 16));
    f[4] = bf2f((unsigned short)(v.z & 0xffff)); f[5] = bf2f((unsigned short)(v.z >> 16));
    f[6] = bf2f((unsigned short)(v.w & 0xffff)); f[7] = bf2f((unsigned short)(v.w >> 16));
}

// ---------------------------------------------------------------------------
// Index dtype detection + canonicalization
// ---------------------------------------------------------------------------
__global__ void detect_kernel(const int* __restrict__ ei, int* __restrict__ flag)
{
    int lane = threadIdx.x;
    int v = ei[2 * lane + 1];
    unsigned long long b = __ballot(v != 0);
    if (lane == 0) *flag = (b != 0ULL) ? 1 : 0;
}

__global__ void normidx_kernel(const int* __restrict__ ei, const int* __restrict__ flag,
                               int* __restrict__ s32, int* __restrict__ d32)
{
    int e = blockIdx.x * blockDim.x + threadIdx.x;
    if (e >= NEDGES) return;
    int s, d;
    if (*flag) { s = ei[e]; d = ei[NEDGES + e]; }
    else       { s = ei[2 * e]; d = ei[2 * (NEDGES + e)]; }
    s32[e] = min(max(s, 0), NNODES - 1);
    d32[e] = min(max(d, 0), NNODES - 1);
}

__global__ void degree_kernel(const int* __restrict__ dst, int* __restrict__ deg)
{
    int e = blockIdx.x * blockDim.x + threadIdx.x;
    if (e < NEDGES) atomicAdd(&deg[dst[e]], 1);
}

// ---------------------------------------------------------------------------
// Exclusive scan over deg[0..NNODES) -> off, cursor. One 1024-thread block.
// ---------------------------------------------------------------------------
#define SCAN_T 1024
__global__ void scan_kernel(const int* __restrict__ deg, int* __restrict__ off,
                            int* __restrict__ cursor)
{
    __shared__ int part[SCAN_T];
    const int t = threadIdx.x;
    const int CH = (NNODES + SCAN_T - 1) / SCAN_T;
    const int base = t * CH;
    int s = 0;
    for (int i = 0; i < CH; ++i) {
        int idx = base + i;
        if (idx < NNODES) s += deg[idx];
    }
    part[t] = s;
    __syncthreads();
    for (int d = 1; d < SCAN_T; d <<= 1) {
        int v = (t >= d) ? part[t - d] : 0;
        __syncthreads();
        part[t] += v;
        __syncthreads();
    }
    int run = (t == 0) ? 0 : part[t - 1];
    for (int i = 0; i < CH; ++i) {
        int idx = base + i;
        if (idx < NNODES) {
            off[idx] = run;
            cursor[idx] = run;
            run += deg[idx];
        }
    }
    if (t == SCAN_T - 1) off[NNODES] = run;
}

__global__ void scatter_kernel(const int* __restrict__ s32, const int* __restrict__ d32,
                               int* __restrict__ cursor,
                               int* __restrict__ sp, int* __restrict__ dp, int* __restrict__ ep)
{
    int e = blockIdx.x * blockDim.x + threadIdx.x;
    if (e >= NEDGES) return;
    int d = d32[e];
    int p = atomicAdd(&cursor[d], 1);
    sp[p] = s32[e];
    dp[p] = d;
    ep[p] = e;
}

// ---------------------------------------------------------------------------
// Weight transpose+convert: W [L][K][N] fp32 -> WT [L][N][K] bf16
// ---------------------------------------------------------------------------
__global__ void transpose_kernel(const float* __restrict__ W, unsigned short* __restrict__ WT,
                                 int K, int N, int L)
{
    long idx = (long)blockIdx.x * 256 + threadIdx.x;
    long tot = (long)L * K * N;
    if (idx >= tot) return;
    int kn = (int)(idx % ((long)K * N));
    int l  = (int)(idx / ((long)K * N));
    int k = kn / N;
    int n = kn % N;
    WT[(long)l * K * N + (long)n * K + k] = f2bf(W[idx]);
}

// ---------------------------------------------------------------------------
// Encoder into permuted layout: ef[p] = enc(ea[ep[p]])
// ---------------------------------------------------------------------------
__global__ void encode_kernel(const float* __restrict__ ea,
                              const float* __restrict__ w,
                              const float* __restrict__ b,
                              const int* __restrict__ ep,
                              unsigned short* __restrict__ ef)
{
    int idx = blockIdx.x * blockDim.x + threadIdx.x;
    int p = idx >> 5;
    if (p >= NEDGES) return;
    int e = ep[p];
    int j = (idx & 31) << 2;
    float a0 = ea[e * 3 + 0], a1 = ea[e * 3 + 1], a2 = ea[e * 3 + 2];
    float4 w0 = *(const float4*)(w + 0 * HIDDEN + j);
    float4 w1 = *(const float4*)(w + 1 * HIDDEN + j);
    float4 w2 = *(const float4*)(w + 2 * HIDDEN + j);
    float4 bb = *(const float4*)(b + j);
    ushort4 o;
    o.x = f2bf(fmaf(a0, w0.x, fmaf(a1, w1.x, fmaf(a2, w2.x, bb.x))));
    o.y = f2bf(fmaf(a0, w0.y, fmaf(a1, w1.y, fmaf(a2, w2.y, bb.y))));
    o.z = f2bf(fmaf(a0, w0.z, fmaf(a1, w1.z, fmaf(a2, w2.z, bb.z))));
    o.w = f2bf(fmaf(a0, w0.w, fmaf(a1, w1.w, fmaf(a2, w2.w, bb.w))));
    *(ushort4*)(ef + (long)p * HIDDEN + j) = o;
}

// ---------------------------------------------------------------------------
// MFMA edge layer, direct-operand form (3 barriers total):
//   GEMM1: A = ef rows (direct global bf16), B = W1c (direct global, L2-hot)
//   H = relu(acc + Xa[dst] + Xb[src] + b1) -> Hs (LDS, C->A relayout)
//   GEMM2: A = Hs, B = W2 (direct global)
//   ef += m ; segmented-reduce m into sums[dst]
// 128 edges x 128 out per block, 4 waves x 32 rows (2 A-frags x 8 B-frags).
// ---------------------------------------------------------------------------
__global__ __launch_bounds__(256, 4)
void edge_layer_mfma(const unsigned short* __restrict__ Xa,   // [N][128] bf16
                     const unsigned short* __restrict__ Xb,   // [N][128] bf16
                     unsigned short* __restrict__ ef,
                     float* __restrict__ sums,
                     const int* __restrict__ sp,
                     const int* __restrict__ dp,
                     const unsigned short* __restrict__ W1T,  // [128][384] bf16; W1c at k+256
                     const float* __restrict__ b1,
                     const unsigned short* __restrict__ W2T,  // [128][128] bf16
                     const float* __restrict__ b2)
{
    __shared__ __align__(16) unsigned short Hs[128 * 136];   // 34816 B
    __shared__ int dv[128];
    __shared__ int sv[128];

    const int tid = threadIdx.x;
    const long eb = (long)blockIdx.x * 128;
    if (tid < 128) dv[tid]       = dp[eb + tid];
    else           sv[tid - 128] = sp[eb + tid - 128];

    const int lane = tid & 63;
    const int wv   = tid >> 6;
    const int mn   = lane & 15;
    const int q    = lane >> 4;

    f32x4 acc[2][8];
#pragma unroll
    for (int h = 0; h < 2; ++h)
#pragma unroll
        for (int t = 0; t < 8; ++t) acc[h][t] = (f32x4)0.0f;

    // ---- GEMM1: ef @ W1c, no LDS, no barriers ----
    {
        const unsigned short* a0p = ef + (eb + wv * 32 + mn) * HIDDEN + (q << 3);
        const unsigned short* a1p = a0p + 16 * HIDDEN;
        const unsigned short* bp  = W1T + (long)mn * 384 + 256 + (q << 3);
#pragma unroll
        for (int c = 0; c < 4; ++c) {
            short8 af0 = *(const short8*)(a0p + (c << 5));
            short8 af1 = *(const short8*)(a1p + (c << 5));
#pragma unroll
            for (int nt = 0; nt < 8; ++nt) {
                short8 bf = *(const short8*)(bp + (long)nt * (16 * 384) + (c << 5));
                acc[0][nt] = __builtin_amdgcn_mfma_f32_16x16x32_bf16(af0, bf, acc[0][nt], 0, 0, 0);
                acc[1][nt] = __builtin_amdgcn_mfma_f32_16x16x32_bf16(af1, bf, acc[1][nt], 0, 0, 0);
            }
        }
    }
    __syncthreads();   // dv/sv visible; Hs region free

    // ---- H = relu(acc + Xa[dst] + Xb[src] + b1) -> Hs bf16 ----
#pragma unroll
    for (int h = 0; h < 2; ++h)
#pragma unroll
        for (int r = 0; r < 4; ++r) {
            const int row = wv * 32 + h * 16 + q * 4 + r;
            const long ba = (long)dv[row] * HIDDEN;
            const long bb = (long)sv[row] * HIDDEN;
#pragma unroll
            for (int nt = 0; nt < 8; ++nt) {
                const int col = nt * 16 + mn;
                float add = bf2f(Xa[ba + col]) + bf2f(Xb[bb + col]) + b1[col];
                float hv = fmaxf(acc[h][nt][r] + add, 0.0f);
                Hs[row * 136 + col] = f2bf(hv);
            }
        }
    __syncthreads();   // Hs(H) complete before cross-lane A-frag reads

    // ---- GEMM2: H @ W2, A from Hs, B direct global ----
    f32x4 acc2[2][8];
#pragma unroll
    for (int h = 0; h < 2; ++h)
#pragma unroll
        for (int t = 0; t < 8; ++t) acc2[h][t] = (f32x4)0.0f;
    {
        const unsigned short* h0p = &Hs[(wv * 32 + mn) * 136 + (q << 3)];
        const unsigned short* h1p = h0p + 16 * 136;
        const unsigned short* bp  = W2T + (long)mn * 128 + (q << 3);
#pragma unroll
        for (int c = 0; c < 4; ++c) {
            short8 af0 = *(const short8*)(h0p + (c << 5));
            short8 af1 = *(const short8*)(h1p + (c << 5));
#pragma unroll
            for (int nt = 0; nt < 8; ++nt) {
                short8 bf = *(const short8*)(bp + nt * (16 * 128) + (c << 5));
                acc2[0][nt] = __builtin_amdgcn_mfma_f32_16x16x32_bf16(af0, bf, acc2[0][nt], 0, 0, 0);
                acc2[1][nt] = __builtin_amdgcn_mfma_f32_16x16x32_bf16(af1, bf, acc2[1][nt], 0, 0, 0);
            }
        }
    }

    // ---- m = acc2 + b2 -> Hs bf16 (wave-private rows; same-wave DS order) ----
#pragma unroll
    for (int h = 0; h < 2; ++h)
#pragma unroll
        for (int nt = 0; nt < 8; ++nt) {
            float b2v = b2[nt * 16 + mn];
#pragma unroll
            for (int r = 0; r < 4; ++r) {
                Hs[(wv * 32 + h * 16 + q * 4 + r) * 136 + nt * 16 + mn] = f2bf(acc2[h][nt][r] + b2v);
            }
        }
    __syncthreads();

    // ---- ef += m (coalesced, full rows) ----
    {
        const int row = tid >> 1;
        const int ch  = (tid & 1) << 6;
        unsigned short* ep_ = ef + (eb + row) * HIDDEN + ch;
        const unsigned short* hp = &Hs[row * 136 + ch];
#pragma unroll
        for (int i = 0; i < 8; ++i) {
            uint4 mh = *(uint4*)(hp + (i << 3));
            uint4 eo = *(const uint4*)(ep_ + (i << 3));
            float m[8], e[8];
            unpack8(mh, m);
            unpack8(eo, e);
            uint4 nw;
            nw.x = pack2(e[0] + m[0], e[1] + m[1]);
            nw.y = pack2(e[2] + m[2], e[3] + m[3]);
            nw.z = pack2(e[4] + m[4], e[5] + m[5]);
            nw.w = pack2(e[6] + m[6], e[7] + m[7]);
            *(uint4*)(ep_ + (i << 3)) = nw;
        }
    }

    // ---- segmented reduction by dst-run: one atomic row per run ----
    {
        const int cp = (tid & 63) << 1;
        const int qr = tid >> 6;
        float s0 = 0.0f, s1 = 0.0f;
        int cur = dv[qr * 32];
        for (int r = 0; r < 32; ++r) {
            const int row = qr * 32 + r;
            const int d = dv[row];
            if (d != cur) {
                atomicAdd(&sums[(long)cur * HIDDEN + cp], s0);
                atomicAdd(&sums[(long)cur * HIDDEN + cp + 1], s1);
                s0 = 0.0f; s1 = 0.0f;
                cur = d;
            }
            unsigned int u = *(unsigned int*)&Hs[row * 136 + cp];
            s0 += bf2f((unsigned short)(u & 0xffff));
            s1 += bf2f((unsigned short)(u >> 16));
        }
        atomicAdd(&sums[(long)cur * HIDDEN + cp], s0);
        atomicAdd(&sums[(long)cur * HIDDEN + cp + 1], s1);
    }
}

// ---------------------------------------------------------------------------
// MFMA node layer, direct-operand form. 64 nodes x 128 out per block.
//   GEMM1: A built in registers from x|sums*cInv, B = N1T direct (no LDS)
//   GEMM2 + Xa/Xb GEMMs: A from Hs, B direct. Zeros sums rows at the end.
// ---------------------------------------------------------------------------
__global__ __launch_bounds__(256, 4)
void node_layer_mfma(float* __restrict__ x,
                     float* __restrict__ sums,
                     const int* __restrict__ deg,
                     const unsigned short* __restrict__ N1T,  // [128][256] bf16
                     const float* __restrict__ b1,
                     const unsigned short* __restrict__ N2T,  // [128][128] bf16
                     const float* __restrict__ b2,
                     const unsigned short* __restrict__ W1Tn, // [128][384] next layer (or null)
                     unsigned short* __restrict__ Xa,
                     unsigned short* __restrict__ Xb)
{
    __shared__ __align__(16) unsigned short Hs[64 * 136];    // 17408 B

    const int tid = threadIdx.x;
    const long n0 = (long)blockIdx.x * 64;
    const int lane = tid & 63;
    const int wv   = tid >> 6;
    const int mn   = lane & 15;
    const int q    = lane >> 4;

    long arow = n0 + wv * 16 + mn;
    if (arow >= NNODES) arow = NNODES - 1;
    const float cInvL = 1.0f / fmaxf((float)deg[arow], 1.0f);

    f32x4 acc[8];
#pragma unroll
    for (int t = 0; t < 8; ++t) acc[t] = (f32x4)0.0f;

    // ---- GEMM1: concat(x, sums*cInv) @ N1, K=256, no LDS, no barriers ----
#pragma unroll
    for (int c = 0; c < 8; ++c) {
        const float* base = (c < 4) ? (x + arow * HIDDEN + (c << 5))
                                    : (sums + arow * HIDDEN + ((c - 4) << 5));
        const float sc = (c < 4) ? 1.0f : cInvL;
        float4 v0 = *(const float4*)(base + (q << 3));
        float4 v1 = *(const float4*)(base + (q << 3) + 4);
        uint4 u;
        u.x = pack2(v0.x * sc, v0.y * sc); u.y = pack2(v0.z * sc, v0.w * sc);
        u.z = pack2(v1.x * sc, v1.y * sc); u.w = pack2(v1.z * sc, v1.w * sc);
        short8 af = *(short8*)&u;
        const unsigned short* bp = N1T + (long)mn * 256 + (c << 5) + (q << 3);
#pragma unroll
        for (int nt = 0; nt < 8; ++nt) {
            short8 bf = *(const short8*)(bp + nt * (16 * 256));
            acc[nt] = __builtin_amdgcn_mfma_f32_16x16x32_bf16(af, bf, acc[nt], 0, 0, 0);
        }
    }

    // ---- H = relu(acc + b1) -> Hs ----
#pragma unroll
    for (int nt = 0; nt < 8; ++nt) {
        float b1v = b1[nt * 16 + mn];
#pragma unroll
        for (int r = 0; r < 4; ++r) {
            float hv = fmaxf(acc[nt][r] + b1v, 0.0f);
            Hs[(wv * 16 + q * 4 + r) * 136 + nt * 16 + mn] = f2bf(hv);
        }
    }
    __syncthreads();

    // ---- GEMM2: H @ N2, A from Hs, B direct ----
    f32x4 acc2[8];
#pragma unroll
    for (int t = 0; t < 8; ++t) acc2[t] = (f32x4)0.0f;
    {
        const unsigned short* hp = &Hs[(wv * 16 + mn) * 136 + (q << 3)];
        const unsigned short* bp = N2T + (long)mn * 128 + (q << 3);
#pragma unroll
        for (int c = 0; c < 4; ++c) {
            short8 af = *(const short8*)(hp + (c << 5));
#pragma unroll
            for (int nt = 0; nt < 8; ++nt) {
                short8 bf = *(const short8*)(bp + nt * (16 * 128) + (c << 5));
                acc2[nt] = __builtin_amdgcn_mfma_f32_16x16x32_bf16(af, bf, acc2[nt], 0, 0, 0);
            }
        }
    }

    // ---- xnew = x + acc2 + b2 (exact fp32); stage xnew bf16 into Hs ----
#pragma unroll
    for (int nt = 0; nt < 8; ++nt) {
        float b2v = b2[nt * 16 + mn];
#pragma unroll
        for (int r = 0; r < 4; ++r) {
            long row = n0 + wv * 16 + q * 4 + r;
            float xn = 0.0f;
            if (row < NNODES) {
                float* p = x + row * HIDDEN + nt * 16 + mn;
                xn = *p + acc2[nt][r] + b2v;
                *p = xn;
            }
            Hs[(wv * 16 + q * 4 + r) * 136 + nt * 16 + mn] = f2bf(xn);
        }
    }
    __syncthreads();

    // ---- Xa/Xb for next layer: xnew @ W1a / W1b ----
    if (W1Tn) {
#pragma unroll
        for (int half = 0; half < 2; ++half) {
            f32x4 accN[8];
#pragma unroll
            for (int t = 0; t < 8; ++t) accN[t] = (f32x4)0.0f;
            const unsigned short* hp = &Hs[(wv * 16 + mn) * 136 + (q << 3)];
            const unsigned short* bp = W1Tn + (long)mn * 384 + (half << 7) + (q << 3);
#pragma unroll
            for (int c = 0; c < 4; ++c) {
                short8 af = *(const short8*)(hp + (c << 5));
#pragma unroll
                for (int nt = 0; nt < 8; ++nt) {
                    short8 bf = *(const short8*)(bp + (long)nt * (16 * 384) + (c << 5));
                    accN[nt] = __builtin_amdgcn_mfma_f32_16x16x32_bf16(af, bf, accN[nt], 0, 0, 0);
                }
            }
            unsigned short* Xout = half ? Xb : Xa;
#pragma unroll
            for (int nt = 0; nt < 8; ++nt) {
#pragma unroll
                for (int r = 0; r < 4; ++r) {
                    long row = n0 + wv * 16 + q * 4 + r;
                    if (row < NNODES) {
                        Xout[row * HIDDEN + nt * 16 + mn] = f2bf(accN[nt][r]);
                    }
                }
            }
        }
    }

    // ---- zero own sums rows for the next layer (all reads long since done) ----
    {
        const int srow = tid >> 2;
        const int sseg = tid & 3;
        long row = n0 + srow;
        if (row < NNODES) {
            float4 z = make_float4(0.f, 0.f, 0.f, 0.f);
            float* p = sums + row * HIDDEN + (sseg << 5);
#pragma unroll
            for (int i = 0; i < 8; ++i) ((float4*)p)[i] = z;
        }
    }
}

// ---------------------------------------------------------------------------
// Decoder + row L2-normalize (one wave per node)
// ---------------------------------------------------------------------------
__global__ void decode_kernel(const float* __restrict__ x,
                              const float* __restrict__ w,
                              const float* __restrict__ b,
                              float* __restrict__ out)
{
    int gid = blockIdx.x * blockDim.x + threadIdx.x;
    int node = gid >> 6;
    int lane = threadIdx.x & 63;
    if (node >= NNODES) return;
    float a0 = 0.f, a1 = 0.f, a2 = 0.f;
#pragma unroll
    for (int k = lane; k < HIDDEN; k += 64) {
        float xv = x[(long)node * HIDDEN + k];
        a0 = fmaf(xv, w[k * 3 + 0], a0);
        a1 = fmaf(xv, w[k * 3 + 1], a1);
        a2 = fmaf(xv, w[k * 3 + 2], a2);
    }
#pragma unroll
    for (int off = 32; off > 0; off >>= 1) {
        a0 += __shfl_down(a0, off);
        a1 += __shfl_down(a1, off);
        a2 += __shfl_down(a2, off);
    }
    if (lane == 0) {
        a0 += b[0]; a1 += b[1]; a2 += b[2];
        float nrm = sqrtf(a0 * a0 + a1 * a1 + a2 * a2);
        float inv = 1.0f / fmaxf(nrm, 1e-12f);
        out[(long)node * 3 + 0] = a0 * inv;
        out[(long)node * 3 + 1] = a1 * inv;
        out[(long)node * 3 + 2] = a2 * inv;
    }
}

// ---------------------------------------------------------------------------
extern "C" void kernel_launch(void* const* d_in, const int* in_sizes, int n_in,
                              void* d_out, int out_size, void* d_ws, size_t ws_size,
                              hipStream_t stream)
{
    const float* edge_attr = (const float*)d_in[1];
    const int*   ei        = (const int*)d_in[2];
    const float* enc_w     = (const float*)d_in[3];
    const float* enc_b     = (const float*)d_in[4];
    const float* dec_w     = (const float*)d_in[5];
    const float* dec_b     = (const float*)d_in[6];
    const float* edge_w1   = (const float*)d_in[7];
    const float* edge_b1   = (const float*)d_in[8];
    const float* edge_w2   = (const float*)d_in[9];
    const float* edge_b2   = (const float*)d_in[10];
    const float* node_w1   = (const float*)d_in[11];
    const float* node_b1   = (const float*)d_in[12];
    const float* node_w2   = (const float*)d_in[13];
    const float* node_b2   = (const float*)d_in[14];

    // workspace layout (bytes), 16B-aligned, total ~255.4 MB
    char* ws = (char*)d_ws;
    unsigned short* ef  = (unsigned short*)(ws);                  // 163,840,000
    float* x      = (float*)(ws + 163840000L);                    //  25,600,000
    float* sums   = (float*)(ws + 189440000L);                    //  25,600,000
    int*   src32  = (int*)  (ws + 215040000L);                    //   2,560,000
    int*   dst32  = (int*)  (ws + 217600000L);                    //   2,560,000
    int*   sp     = (int*)  (ws + 220160000L);                    //   2,560,000
    int*   dp     = (int*)  (ws + 222720000L);                    //   2,560,000
    int*   eperm  = (int*)  (ws + 225280000L);                    //   2,560,000
    int*   deg    = (int*)  (ws + 227840000L);                    //     200,704
    int*   off    = (int*)  (ws + 228040704L);                    //     200,704
    int*   cursor = (int*)  (ws + 228241408L);                    //     200,704
    int*   flag   = (int*)  (ws + 228442112L);                    //          64
    unsigned short* W1T = (unsigned short*)(ws + 228442176L);     //     589,824
    unsigned short* W2T = (unsigned short*)(ws + 229032000L);     //     196,608
    unsigned short* N1T = (unsigned short*)(ws + 229228608L);     //     393,216
    unsigned short* N2T = (unsigned short*)(ws + 229621824L);     //     196,608
    unsigned short* Xa  = (unsigned short*)(ws + 229818432L);     //  12,800,000
    unsigned short* Xb  = (unsigned short*)(ws + 242618432L);     //  12,800,000
    // end: 255,418,432

    float* out = (float*)d_out;

    hipMemsetAsync(x, 0, (size_t)NNODES * HIDDEN * sizeof(float), stream);
    hipMemsetAsync(sums, 0, (size_t)NNODES * HIDDEN * sizeof(float), stream);
    hipMemsetAsync(deg, 0, 200704, stream);
    hipMemsetAsync(Xa, 0, 25600000, stream);   // Xa + Xb (contiguous)

    detect_kernel<<<1, 64, 0, stream>>>(ei, flag);
    normidx_kernel<<<(NEDGES + 255) / 256, 256, 0, stream>>>(ei, flag, src32, dst32);
    degree_kernel<<<(NEDGES + 255) / 256, 256, 0, stream>>>(dst32, deg);
    scan_kernel<<<1, SCAN_T, 0, stream>>>(deg, off, cursor);
    scatter_kernel<<<(NEDGES + 255) / 256, 256, 0, stream>>>(src32, dst32, cursor, sp, dp, eperm);
    encode_kernel<<<(NEDGES * 32 + 255) / 256, 256, 0, stream>>>(edge_attr, enc_w, enc_b, eperm, ef);

    transpose_kernel<<<(6 * 384 * 128 + 255) / 256, 256, 0, stream>>>(edge_w1, W1T, 384, 128, 6);
    transpose_kernel<<<(6 * 128 * 128 + 255) / 256, 256, 0, stream>>>(edge_w2, W2T, 128, 128, 6);
    transpose_kernel<<<(6 * 256 * 128 + 255) / 256, 256, 0, stream>>>(node_w1, N1T, 256, 128, 6);
    transpose_kernel<<<(6 * 128 * 128 + 255) / 256, 256, 0, stream>>>(node_w2, N2T, 128, 128, 6);

    for (int l = 0; l < NLAYERS; ++l) {
        edge_layer_mfma<<<NEDGES / 128, 256, 0, stream>>>(
            Xa, Xb, ef, sums, sp, dp,
            W1T + (long)l * 384 * 128, edge_b1 + (long)l * HIDDEN,
            W2T + (long)l * 128 * 128, edge_b2 + (long)l * HIDDEN);
        const unsigned short* w1next = (l + 1 < NLAYERS) ? (W1T + (long)(l + 1) * 384 * 128) : nullptr;
        node_layer_mfma<<<(NNODES + 63) / 64, 256, 0, stream>>>(
            x, sums, deg,
            N1T + (long)l * 256 * 128, node_b1 + (long)l * HIDDEN,
            N2T + (long)l * 128 * 128, node_b2 + (long)l * HIDDEN,
            w1next, Xa, Xb);
    }

    decode_kernel<<<(NNODES * 64 + 255) / 256, 256, 0, stream>>>(x, dec_w, dec_b, out);
}

// Round 8
// 1950.900 us; speedup vs baseline: 1.5162x; 1.5162x over previous
//
#include <hip/hip_runtime.h>
#include <cstdint>

#define HIDDEN  128
#define NLAYERS 6
#define NNODES  50000
#define NEDGES  640000

typedef short short8 __attribute__((ext_vector_type(8)));
typedef float f32x4  __attribute__((ext_vector_type(4)));

// ---- bf16 <-> f32 helpers (RNE) -------------------------------------------
__device__ __forceinline__ float bf2f(unsigned short u) {
    return __uint_as_float(((unsigned int)u) << 16);
}
__device__ __forceinline__ unsigned short f2bf(float f) {
    unsigned int u = __float_as_uint(f);
    unsigned int r = u + 0x7FFFu + ((u >> 16) & 1u);
    return (unsigned short)(r >> 16);
}
__device__ __forceinline__ unsigned int pack2(float a, float b) {
    return (unsigned int)f2bf(a) | ((unsigned int)f2bf(b) << 16);
}
__device__ __forceinline__ void unpack8(uint4 v, float* f) {
    f[0] = bf2f((unsigned short)(v.x & 0xffff)); f[1] = bf2f((unsigned short)(v.x >> 16));
    f[2] = bf2f((unsigned short)(v.y & 0xffff)); f[3] = bf2f((unsigned short)(v.y >> 16));
    f[4] = bf2f((unsigned short)(v.z & 0xffff)); f[5] = bf2f((unsigned short)(v.z >> 16));
    f[6] = bf2f((unsigned short)(v.w & 0xffff)); f[7] = bf2f((unsigned short)(v.w >> 16));
}

// ---------------------------------------------------------------------------
// Index dtype detection + canonicalization
// ---------------------------------------------------------------------------
__global__ void detect_kernel(const int* __restrict__ ei, int* __restrict__ flag)
{
    int lane = threadIdx.x;
    int v = ei[2 * lane + 1];
    unsigned long long b = __ballot(v != 0);
    if (lane == 0) *flag = (b != 0ULL) ? 1 : 0;
}

__global__ void normidx_kernel(const int* __restrict__ ei, const int* __restrict__ flag,
                               int* __restrict__ s32, int* __restrict__ d32)
{
    int e = blockIdx.x * blockDim.x + threadIdx.x;
    if (e >= NEDGES) return;
    int s, d;
    if (*flag) { s = ei[e]; d = ei[NEDGES + e]; }
    else       { s = ei[2 * e]; d = ei[2 * (NEDGES + e)]; }
    s32[e] = min(max(s, 0), NNODES - 1);
    d32[e] = min(max(d, 0), NNODES - 1);
}

__global__ void degree_kernel(const int* __restrict__ dst, int* __restrict__ deg)
{
    int e = blockIdx.x * blockDim.x + threadIdx.x;
    if (e < NEDGES) atomicAdd(&deg[dst[e]], 1);
}

// ---------------------------------------------------------------------------
// Exclusive scan over deg[0..NNODES) -> off, cursor. One 1024-thread block.
// ---------------------------------------------------------------------------
#define SCAN_T 1024
__global__ void scan_kernel(const int* __restrict__ deg, int* __restrict__ off,
                            int* __restrict__ cursor)
{
    __shared__ int part[SCAN_T];
    const int t = threadIdx.x;
    const int CH = (NNODES + SCAN_T - 1) / SCAN_T;
    const int base = t * CH;
    int s = 0;
    for (int i = 0; i < CH; ++i) {
        int idx = base + i;
        if (idx < NNODES) s += deg[idx];
    }
    part[t] = s;
    __syncthreads();
    for (int d = 1; d < SCAN_T; d <<= 1) {
        int v = (t >= d) ? part[t - d] : 0;
        __syncthreads();
        part[t] += v;
        __syncthreads();
    }
    int run = (t == 0) ? 0 : part[t - 1];
    for (int i = 0; i < CH; ++i) {
        int idx = base + i;
        if (idx < NNODES) {
            off[idx] = run;
            cursor[idx] = run;
            run += deg[idx];
        }
    }
    if (t == SCAN_T - 1) off[NNODES] = run;
}

__global__ void scatter_kernel(const int* __restrict__ s32, const int* __restrict__ d32,
                               int* __restrict__ cursor,
                               int* __restrict__ sp, int* __restrict__ dp, int* __restrict__ ep)
{
    int e = blockIdx.x * blockDim.x + threadIdx.x;
    if (e >= NEDGES) return;
    int d = d32[e];
    int p = atomicAdd(&cursor[d], 1);
    sp[p] = s32[e];
    dp[p] = d;
    ep[p] = e;
}

// ---------------------------------------------------------------------------
// Weight transpose+convert: W [L][K][N] fp32 -> WT [L][N][K] bf16
// ---------------------------------------------------------------------------
__global__ void transpose_kernel(const float* __restrict__ W, unsigned short* __restrict__ WT,
                                 int K, int N, int L)
{
    long idx = (long)blockIdx.x * 256 + threadIdx.x;
    long tot = (long)L * K * N;
    if (idx >= tot) return;
    int kn = (int)(idx % ((long)K * N));
    int l  = (int)(idx / ((long)K * N));
    int k = kn / N;
    int n = kn % N;
    WT[(long)l * K * N + (long)n * K + k] = f2bf(W[idx]);
}

// ---------------------------------------------------------------------------
// Encoder into permuted layout: ef[p] = enc(ea[ep[p]])
// ---------------------------------------------------------------------------
__global__ void encode_kernel(const float* __restrict__ ea,
                              const float* __restrict__ w,
                              const float* __restrict__ b,
                              const int* __restrict__ ep,
                              unsigned short* __restrict__ ef)
{
    int idx = blockIdx.x * blockDim.x + threadIdx.x;
    int p = idx >> 5;
    if (p >= NEDGES) return;
    int e = ep[p];
    int j = (idx & 31) << 2;
    float a0 = ea[e * 3 + 0], a1 = ea[e * 3 + 1], a2 = ea[e * 3 + 2];
    float4 w0 = *(const float4*)(w + 0 * HIDDEN + j);
    float4 w1 = *(const float4*)(w + 1 * HIDDEN + j);
    float4 w2 = *(const float4*)(w + 2 * HIDDEN + j);
    float4 bb = *(const float4*)(b + j);
    ushort4 o;
    o.x = f2bf(fmaf(a0, w0.x, fmaf(a1, w1.x, fmaf(a2, w2.x, bb.x))));
    o.y = f2bf(fmaf(a0, w0.y, fmaf(a1, w1.y, fmaf(a2, w2.y, bb.y))));
    o.z = f2bf(fmaf(a0, w0.z, fmaf(a1, w1.z, fmaf(a2, w2.z, bb.z))));
    o.w = f2bf(fmaf(a0, w0.w, fmaf(a1, w1.w, fmaf(a2, w2.w, bb.w))));
    *(ushort4*)(ef + (long)p * HIDDEN + j) = o;
}

// ---------------------------------------------------------------------------
// MFMA edge layer on dst-sorted edges, factored form, 64-edge tile:
//   pre = ef @ W1c (K=128, LDS-staged, 4 k-steps)
//   H   = relu(pre + Xa[dst] + Xb[src] + b1)
//   m   = H @ W2 + b2 ; ef += m ; segmented-reduce m into sums[dst]
// 4 waves x 16 rows; As/GEMM2-A reads are wave-private (fewer barriers).
// LDS 28.2 KB -> 5 blocks/CU for latency hiding.
// ---------------------------------------------------------------------------
__global__ __launch_bounds__(256, 5)
void edge_layer_mfma(const unsigned short* __restrict__ Xa,   // [N][128] bf16
                     const unsigned short* __restrict__ Xb,   // [N][128] bf16
                     unsigned short* __restrict__ ef,
                     float* __restrict__ sums,
                     const int* __restrict__ sp,
                     const int* __restrict__ dp,
                     const unsigned short* __restrict__ W1T,  // [128][384] bf16; W1c at k+256
                     const float* __restrict__ b1,
                     const unsigned short* __restrict__ W2T,  // [128][128] bf16
                     const float* __restrict__ b2)
{
    // 0     .. 17408 : Hs (64 x 136) / As (64 x 40, 5120 B) aliased
    // 17408 .. 27648 : Bs (128 x 40)
    __shared__ __align__(16) unsigned char buf[27648];
    unsigned short* As = (unsigned short*)buf;
    unsigned short* Hs = (unsigned short*)buf;
    unsigned short* Bs = (unsigned short*)(buf + 17408);
    __shared__ int dv[64];
    __shared__ int sv[64];

    const int tid = threadIdx.x;
    const long eb = (long)blockIdx.x * 64;
    if (tid < 64)        dv[tid]      = dp[eb + tid];
    else if (tid < 128)  sv[tid - 64] = sp[eb + tid - 64];

    const int lane = tid & 63;
    const int wv   = tid >> 6;
    const int mn   = lane & 15;
    const int q    = lane >> 4;
    const int sr   = tid >> 2;          // As staging row 0..63 (wave-private!)
    const int ss   = (tid & 3) << 3;    // 8-short segment
    const int bn   = tid >> 1;          // Bs row 0..127
    const int bk   = (tid & 1) << 4;    // 0 or 16

    f32x4 acc[8];
#pragma unroll
    for (int t = 0; t < 8; ++t) acc[t] = (f32x4)0.0f;

    uint4 pa, pw0, pw1;
    {   // chunk 0 loads
        pa = *(const uint4*)(ef + (eb + sr) * HIDDEN + ss);
        const unsigned short* wp = W1T + (long)bn * 384 + 256 + bk;
        pw0 = *(const uint4*)wp;
        pw1 = *(const uint4*)(wp + 8);
    }

    // ---- GEMM1: ef @ W1c, 4 k-steps of 32, register-prefetched ----
    for (int c = 0; c < 4; ++c) {
        *(uint4*)&As[sr * 40 + ss]     = pa;
        *(uint4*)&Bs[bn * 40 + bk]     = pw0;
        *(uint4*)&Bs[bn * 40 + bk + 8] = pw1;
        __syncthreads();

        if (c + 1 < 4) {
            const int cn = c + 1;
            pa = *(const uint4*)(ef + (eb + sr) * HIDDEN + (cn << 5) + ss);
            const unsigned short* wp = W1T + (long)bn * 384 + 256 + (cn << 5) + bk;
            pw0 = *(const uint4*)wp;
            pw1 = *(const uint4*)(wp + 8);
        }

        short8 af = *(short8*)&As[(wv * 16 + mn) * 40 + (q << 3)];
#pragma unroll
        for (int nt = 0; nt < 8; ++nt) {
            short8 bf = *(short8*)&Bs[(nt * 16 + mn) * 40 + (q << 3)];
            acc[nt] = __builtin_amdgcn_mfma_f32_16x16x32_bf16(af, bf, acc[nt], 0, 0, 0);
        }
        __syncthreads();
    }
    // (final barrier above: all waves done with As region -> Hs alias safe)

    // ---- H = relu(acc + Xa[dst] + Xb[src] + b1) -> Hs bf16 (wave-private rows)
#pragma unroll
    for (int r = 0; r < 4; ++r) {
        const int row = wv * 16 + q * 4 + r;
        const long ba = (long)dv[row] * HIDDEN;
        const long bb = (long)sv[row] * HIDDEN;
#pragma unroll
        for (int nt = 0; nt < 8; ++nt) {
            const int col = nt * 16 + mn;
            float add = bf2f(Xa[ba + col]) + bf2f(Xb[bb + col]) + b1[col];
            float hv = fmaxf(acc[nt][r] + add, 0.0f);
            Hs[row * 136 + col] = f2bf(hv);
        }
    }
    // No barrier: GEMM2 A-frags read only this wave's own Hs rows.

    // ---- GEMM2: H @ W2, 4 k-steps of 32, Bs staged+prefetched ----
    f32x4 acc2[8];
#pragma unroll
    for (int t = 0; t < 8; ++t) acc2[t] = (f32x4)0.0f;
    {
        const unsigned short* wp = W2T + (long)bn * 128 + bk;
        pw0 = *(const uint4*)wp;
        pw1 = *(const uint4*)(wp + 8);
    }
    for (int c = 0; c < 4; ++c) {
        *(uint4*)&Bs[bn * 40 + bk]     = pw0;
        *(uint4*)&Bs[bn * 40 + bk + 8] = pw1;
        __syncthreads();
        if (c + 1 < 4) {
            const unsigned short* wp = W2T + (long)bn * 128 + ((c + 1) << 5) + bk;
            pw0 = *(const uint4*)wp;
            pw1 = *(const uint4*)(wp + 8);
        }
        short8 af = *(short8*)&Hs[(wv * 16 + mn) * 136 + (c << 5) + (q << 3)];
#pragma unroll
        for (int nt = 0; nt < 8; ++nt) {
            short8 bf = *(short8*)&Bs[(nt * 16 + mn) * 40 + (q << 3)];
            acc2[nt] = __builtin_amdgcn_mfma_f32_16x16x32_bf16(af, bf, acc2[nt], 0, 0, 0);
        }
        __syncthreads();
    }

    // ---- m = acc2 + b2 -> Hs bf16 (wave-private rows, same-wave DS order) ----
#pragma unroll
    for (int nt = 0; nt < 8; ++nt) {
        float b2v = b2[nt * 16 + mn];
#pragma unroll
        for (int r = 0; r < 4; ++r) {
            Hs[(wv * 16 + q * 4 + r) * 136 + nt * 16 + mn] = f2bf(acc2[nt][r] + b2v);
        }
    }
    __syncthreads();

    // ---- ef += m (coalesced: 4 threads/row x 64 B) ----
    {
        const int row = tid >> 2;
        const int cq  = (tid & 3) << 5;     // column quarter: 0,32,64,96
        unsigned short* ep_ = ef + (eb + row) * HIDDEN + cq;
        const unsigned short* hp = &Hs[row * 136 + cq];
#pragma unroll
        for (int i = 0; i < 4; ++i) {
            uint4 mh = *(uint4*)(hp + (i << 3));
            uint4 eo = *(const uint4*)(ep_ + (i << 3));
            float m[8], e[8];
            unpack8(mh, m);
            unpack8(eo, e);
            uint4 nw;
            nw.x = pack2(e[0] + m[0], e[1] + m[1]);
            nw.y = pack2(e[2] + m[2], e[3] + m[3]);
            nw.z = pack2(e[4] + m[4], e[5] + m[5]);
            nw.w = pack2(e[6] + m[6], e[7] + m[7]);
            *(uint4*)(ep_ + (i << 3)) = nw;
        }
    }

    // ---- segmented reduction by dst-run: one atomic row per run ----
    {
        const int cp = (tid & 63) << 1;     // column pair
        const int qr = tid >> 6;            // 16-row quarter
        float s0 = 0.0f, s1 = 0.0f;
        int cur = dv[qr * 16];
        for (int r = 0; r < 16; ++r) {
            const int row = qr * 16 + r;
            const int d = dv[row];
            if (d != cur) {
                atomicAdd(&sums[(long)cur * HIDDEN + cp], s0);
                atomicAdd(&sums[(long)cur * HIDDEN + cp + 1], s1);
                s0 = 0.0f; s1 = 0.0f;
                cur = d;
            }
            unsigned int u = *(unsigned int*)&Hs[row * 136 + cp];
            s0 += bf2f((unsigned short)(u & 0xffff));
            s1 += bf2f((unsigned short)(u >> 16));
        }
        atomicAdd(&sums[(long)cur * HIDDEN + cp], s0);
        atomicAdd(&sums[(long)cur * HIDDEN + cp + 1], s1);
    }
}

// ---------------------------------------------------------------------------
// MFMA node layer (round-6 staged form). 64 nodes x 128 out per block.
//   - zeros its sums rows after consuming them
//   - computes Xa = xnew @ W1a(l+1), Xb = xnew @ W1b(l+1) for the next layer
// ---------------------------------------------------------------------------
__global__ __launch_bounds__(256, 4)
void node_layer_mfma(float* __restrict__ x,
                     float* __restrict__ sums,
                     const int* __restrict__ deg,
                     const unsigned short* __restrict__ N1T,  // [128][256] bf16
                     const float* __restrict__ b1,
                     const unsigned short* __restrict__ N2T,  // [128][128] bf16
                     const float* __restrict__ b2,
                     const unsigned short* __restrict__ W1Tn, // [128][384] next layer (or null)
                     unsigned short* __restrict__ Xa,
                     unsigned short* __restrict__ Xb)
{
    __shared__ __align__(16) unsigned short As[64 * 40];
    __shared__ __align__(16) unsigned short Bs[128 * 40];
    __shared__ __align__(16) unsigned short Hs[64 * 136];
    __shared__ float cInv[64];

    const int tid = threadIdx.x;
    const long n0 = (long)blockIdx.x * 64;
    if (tid < 64) {
        long n = n0 + tid;
        cInv[tid] = (n < NNODES) ? 1.0f / fmaxf((float)deg[n], 1.0f) : 0.0f;
    }

    const int lane = tid & 63;
    const int wv   = tid >> 6;
    const int mn   = lane & 15;
    const int q    = lane >> 4;
    const int srow = tid >> 2;
    const int sseg = tid & 3;
    const int bn   = tid >> 1;
    const int bk   = (tid & 1) << 4;

    long nr = n0 + srow;
    if (nr >= NNODES) nr = NNODES - 1;

    __syncthreads();

    f32x4 acc[8];
#pragma unroll
    for (int t = 0; t < 8; ++t) acc[t] = (f32x4)0.0f;

    float4 pa0, pa1;
    uint4 pb0, pb1;
    {
        const float* spx = x + nr * HIDDEN + (sseg << 3);
        pa0 = *(const float4*)spx;
        pa1 = *(const float4*)(spx + 4);
        const unsigned short* wp = N1T + (long)bn * 256 + bk;
        pb0 = *(const uint4*)wp;
        pb1 = *(const uint4*)(wp + 8);
    }
    float scCur = 1.0f;
    for (int c = 0; c < 8; ++c) {
        {
            uint4 w;
            w.x = pack2(pa0.x * scCur, pa0.y * scCur); w.y = pack2(pa0.z * scCur, pa0.w * scCur);
            w.z = pack2(pa1.x * scCur, pa1.y * scCur); w.w = pack2(pa1.z * scCur, pa1.w * scCur);
            *(uint4*)&As[srow * 40 + (sseg << 3)] = w;
        }
        *(uint4*)&Bs[bn * 40 + bk]     = pb0;
        *(uint4*)&Bs[bn * 40 + bk + 8] = pb1;
        __syncthreads();
        if (c + 1 < 8) {
            const int cn = c + 1;
            const float* base = (cn < 4) ? x : sums;
            scCur = (cn < 4) ? 1.0f : cInv[srow];
            const float* spx = base + nr * HIDDEN + ((cn & 3) << 5) + (sseg << 3);
            pa0 = *(const float4*)spx;
            pa1 = *(const float4*)(spx + 4);
            const unsigned short* wp = N1T + (long)bn * 256 + (cn << 5) + bk;
            pb0 = *(const uint4*)wp;
            pb1 = *(const uint4*)(wp + 8);
        }
        short8 af = *(short8*)&As[(wv * 16 + mn) * 40 + (q << 3)];
#pragma unroll
        for (int nt = 0; nt < 8; ++nt) {
            short8 bf = *(short8*)&Bs[(nt * 16 + mn) * 40 + (q << 3)];
            acc[nt] = __builtin_amdgcn_mfma_f32_16x16x32_bf16(af, bf, acc[nt], 0, 0, 0);
        }
        __syncthreads();
    }

    // zero own sums rows for the next layer
    {
        long row = n0 + srow;
        if (row < NNODES) {
            float4 z = make_float4(0.f, 0.f, 0.f, 0.f);
            float* p = sums + row * HIDDEN + (sseg << 5);
#pragma unroll
            for (int i = 0; i < 8; ++i) ((float4*)p)[i] = z;
        }
    }

#pragma unroll
    for (int nt = 0; nt < 8; ++nt) {
        float b1v = b1[nt * 16 + mn];
#pragma unroll
        for (int r = 0; r < 4; ++r) {
            float hv = fmaxf(acc[nt][r] + b1v, 0.0f);
            Hs[(wv * 16 + q * 4 + r) * 136 + nt * 16 + mn] = f2bf(hv);
        }
    }

    f32x4 acc2[8];
#pragma unroll
    for (int t = 0; t < 8; ++t) acc2[t] = (f32x4)0.0f;
    {
        const unsigned short* wp = N2T + (long)bn * 128 + bk;
        pb0 = *(const uint4*)wp;
        pb1 = *(const uint4*)(wp + 8);
    }
    for (int c = 0; c < 4; ++c) {
        *(uint4*)&Bs[bn * 40 + bk]     = pb0;
        *(uint4*)&Bs[bn * 40 + bk + 8] = pb1;
        __syncthreads();
        if (c + 1 < 4) {
            const unsigned short* wp = N2T + (long)bn * 128 + ((c + 1) << 5) + bk;
            pb0 = *(const uint4*)wp;
            pb1 = *(const uint4*)(wp + 8);
        }
        short8 af = *(short8*)&Hs[(wv * 16 + mn) * 136 + (c << 5) + (q << 3)];
#pragma unroll
        for (int nt = 0; nt < 8; ++nt) {
            short8 bf = *(short8*)&Bs[(nt * 16 + mn) * 40 + (q << 3)];
            acc2[nt] = __builtin_amdgcn_mfma_f32_16x16x32_bf16(af, bf, acc2[nt], 0, 0, 0);
        }
        __syncthreads();
    }

    // ---- xnew = x + acc2 + b2 (exact fp32); stage xnew bf16 into Hs ----
#pragma unroll
    for (int nt = 0; nt < 8; ++nt) {
        float b2v = b2[nt * 16 + mn];
#pragma unroll
        for (int r = 0; r < 4; ++r) {
            long row = n0 + wv * 16 + q * 4 + r;
            float xn = 0.0f;
            if (row < NNODES) {
                float* p = x + row * HIDDEN + nt * 16 + mn;
                xn = *p + acc2[nt][r] + b2v;
                *p = xn;
            }
            Hs[(wv * 16 + q * 4 + r) * 136 + nt * 16 + mn] = f2bf(xn);
        }
    }

    // ---- Xa/Xb for next layer: xnew @ W1a / W1b ----
    if (W1Tn) {
#pragma unroll
        for (int half = 0; half < 2; ++half) {
            f32x4 accN[8];
#pragma unroll
            for (int t = 0; t < 8; ++t) accN[t] = (f32x4)0.0f;
            const int kbase = half << 7;
            {
                const unsigned short* wp = W1Tn + (long)bn * 384 + kbase + bk;
                pb0 = *(const uint4*)wp;
                pb1 = *(const uint4*)(wp + 8);
            }
            for (int c = 0; c < 4; ++c) {
                *(uint4*)&Bs[bn * 40 + bk]     = pb0;
                *(uint4*)&Bs[bn * 40 + bk + 8] = pb1;
                __syncthreads();
                if (c + 1 < 4) {
                    const unsigned short* wp = W1Tn + (long)bn * 384 + kbase + ((c + 1) << 5) + bk;
                    pb0 = *(const uint4*)wp;
                    pb1 = *(const uint4*)(wp + 8);
                }
                short8 af = *(short8*)&Hs[(wv * 16 + mn) * 136 + (c << 5) + (q << 3)];
#pragma unroll
                for (int nt = 0; nt < 8; ++nt) {
                    short8 bf = *(short8*)&Bs[(nt * 16 + mn) * 40 + (q << 3)];
                    accN[nt] = __builtin_amdgcn_mfma_f32_16x16x32_bf16(af, bf, accN[nt], 0, 0, 0);
                }
                __syncthreads();
            }
            unsigned short* Xout = half ? Xb : Xa;
#pragma unroll
            for (int nt = 0; nt < 8; ++nt) {
#pragma unroll
                for (int r = 0; r < 4; ++r) {
                    long row = n0 + wv * 16 + q * 4 + r;
                    if (row < NNODES) {
                        Xout[row * HIDDEN + nt * 16 + mn] = f2bf(accN[nt][r]);
                    }
                }
            }
        }
    }
}

// ---------------------------------------------------------------------------
// Decoder + row L2-normalize (one wave per node)
// ---------------------------------------------------------------------------
__global__ void decode_kernel(const float* __restrict__ x,
                              const float* __restrict__ w,
                              const float* __restrict__ b,
                              float* __restrict__ out)
{
    int gid = blockIdx.x * blockDim.x + threadIdx.x;
    int node = gid >> 6;
    int lane = threadIdx.x & 63;
    if (node >= NNODES) return;
    float a0 = 0.f, a1 = 0.f, a2 = 0.f;
#pragma unroll
    for (int k = lane; k < HIDDEN; k += 64) {
        float xv = x[(long)node * HIDDEN + k];
        a0 = fmaf(xv, w[k * 3 + 0], a0);
        a1 = fmaf(xv, w[k * 3 + 1], a1);
        a2 = fmaf(xv, w[k * 3 + 2], a2);
    }
#pragma unroll
    for (int off = 32; off > 0; off >>= 1) {
        a0 += __shfl_down(a0, off);
        a1 += __shfl_down(a1, off);
        a2 += __shfl_down(a2, off);
    }
    if (lane == 0) {
        a0 += b[0]; a1 += b[1]; a2 += b[2];
        float nrm = sqrtf(a0 * a0 + a1 * a1 + a2 * a2);
        float inv = 1.0f / fmaxf(nrm, 1e-12f);
        out[(long)node * 3 + 0] = a0 * inv;
        out[(long)node * 3 + 1] = a1 * inv;
        out[(long)node * 3 + 2] = a2 * inv;
    }
}

// ---------------------------------------------------------------------------
extern "C" void kernel_launch(void* const* d_in, const int* in_sizes, int n_in,
                              void* d_out, int out_size, void* d_ws, size_t ws_size,
                              hipStream_t stream)
{
    const float* edge_attr = (const float*)d_in[1];
    const int*   ei        = (const int*)d_in[2];
    const float* enc_w     = (const float*)d_in[3];
    const float* enc_b     = (const float*)d_in[4];
    const float* dec_w     = (const float*)d_in[5];
    const float* dec_b     = (const float*)d_in[6];
    const float* edge_w1   = (const float*)d_in[7];
    const float* edge_b1   = (const float*)d_in[8];
    const float* edge_w2   = (const float*)d_in[9];
    const float* edge_b2   = (const float*)d_in[10];
    const float* node_w1   = (const float*)d_in[11];
    const float* node_b1   = (const float*)d_in[12];
    const float* node_w2   = (const float*)d_in[13];
    const float* node_b2   = (const float*)d_in[14];

    // workspace layout (bytes), 16B-aligned, total ~255.4 MB
    char* ws = (char*)d_ws;
    unsigned short* ef  = (unsigned short*)(ws);                  // 163,840,000
    float* x      = (float*)(ws + 163840000L);                    //  25,600,000
    float* sums   = (float*)(ws + 189440000L);                    //  25,600,000
    int*   src32  = (int*)  (ws + 215040000L);                    //   2,560,000
    int*   dst32  = (int*)  (ws + 217600000L);                    //   2,560,000
    int*   sp     = (int*)  (ws + 220160000L);                    //   2,560,000
    int*   dp     = (int*)  (ws + 222720000L);                    //   2,560,000
    int*   eperm  = (int*)  (ws + 225280000L);                    //   2,560,000
    int*   deg    = (int*)  (ws + 227840000L);                    //     200,704
    int*   off    = (int*)  (ws + 228040704L);                    //     200,704
    int*   cursor = (int*)  (ws + 228241408L);                    //     200,704
    int*   flag   = (int*)  (ws + 228442112L);                    //          64
    unsigned short* W1T = (unsigned short*)(ws + 228442176L);     //     589,824
    unsigned short* W2T = (unsigned short*)(ws + 229032000L);     //     196,608
    unsigned short* N1T = (unsigned short*)(ws + 229228608L);     //     393,216
    unsigned short* N2T = (unsigned short*)(ws + 229621824L);     //     196,608
    unsigned short* Xa  = (unsigned short*)(ws + 229818432L);     //  12,800,000
    unsigned short* Xb  = (unsigned short*)(ws + 242618432L);     //  12,800,000
    // end: 255,418,432

    float* out = (float*)d_out;

    hipMemsetAsync(x, 0, (size_t)NNODES * HIDDEN * sizeof(float), stream);
    hipMemsetAsync(sums, 0, (size_t)NNODES * HIDDEN * sizeof(float), stream);
    hipMemsetAsync(deg, 0, 200704, stream);
    hipMemsetAsync(Xa, 0, 25600000, stream);   // Xa + Xb (contiguous)

    detect_kernel<<<1, 64, 0, stream>>>(ei, flag);
    normidx_kernel<<<(NEDGES + 255) / 256, 256, 0, stream>>>(ei, flag, src32, dst32);
    degree_kernel<<<(NEDGES + 255) / 256, 256, 0, stream>>>(dst32, deg);
    scan_kernel<<<1, SCAN_T, 0, stream>>>(deg, off, cursor);
    scatter_kernel<<<(NEDGES + 255) / 256, 256, 0, stream>>>(src32, dst32, cursor, sp, dp, eperm);
    encode_kernel<<<(NEDGES * 32 + 255) / 256, 256, 0, stream>>>(edge_attr, enc_w, enc_b, eperm, ef);

    transpose_kernel<<<(6 * 384 * 128 + 255) / 256, 256, 0, stream>>>(edge_w1, W1T, 384, 128, 6);
    transpose_kernel<<<(6 * 128 * 128 + 255) / 256, 256, 0, stream>>>(edge_w2, W2T, 128, 128, 6);
    transpose_kernel<<<(6 * 256 * 128 + 255) / 256, 256, 0, stream>>>(node_w1, N1T, 256, 128, 6);
    transpose_kernel<<<(6 * 128 * 128 + 255) / 256, 256, 0, stream>>>(node_w2, N2T, 128, 128, 6);

    for (int l = 0; l < NLAYERS; ++l) {
        edge_layer_mfma<<<NEDGES / 64, 256, 0, stream>>>(
            Xa, Xb, ef, sums, sp, dp,
            W1T + (long)l * 384 * 128, edge_b1 + (long)l * HIDDEN,
            W2T + (long)l * 128 * 128, edge_b2 + (long)l * HIDDEN);
        const unsigned short* w1next = (l + 1 < NLAYERS) ? (W1T + (long)(l + 1) * 384 * 128) : nullptr;
        node_layer_mfma<<<(NNODES + 63) / 64, 256, 0, stream>>>(
            x, sums, deg,
            N1T + (long)l * 256 * 128, node_b1 + (long)l * HIDDEN,
            N2T + (long)l * 128 * 128, node_b2 + (long)l * HIDDEN,
            w1next, Xa, Xb);
    }

    decode_kernel<<<(NNODES * 64 + 255) / 256, 256, 0, stream>>>(x, dec_w, dec_b, out);
}